// Round 4
// baseline (106.436 us; speedup 1.0000x reference)
//
#include <hip/hip_runtime.h>
#include <stdint.h>

#define NBINS 100
#define FF 16
#define CC 16
#define MM_BLOCKS 256
#define HIST_BLOCKS 256

// ---------- workspace layout (bytes) ----------
// [0     ) unsigned partials[256*32]   : 32768 B (per-block min/max, order-encoded)
// [32768 ) unsigned counts[16*100]     : 6400 B
// [39168 ) int8     sbins[(N+16)*16]   : 1600256 B (side-left bin per element, [-1,99])

// order-preserving float<->uint encoding (no NaNs in inputs)
__device__ __forceinline__ unsigned enc_f(float v) {
    unsigned u = __float_as_uint(v);
    return (u & 0x80000000u) ? ~u : (u | 0x80000000u);
}
__device__ __forceinline__ float dec_f(unsigned e) {
    unsigned u = (e & 0x80000000u) ? (e ^ 0x80000000u) : ~e;
    return __uint_as_float(u);
}
__device__ __forceinline__ unsigned shfl_xor_u(unsigned x, int m) {
    return (unsigned)__shfl_xor((int)x, m, 64);
}
// exact JAX linspace edge: lo + (hi-lo)*t_k, t_k = k*0.01f (f32), t_100 = 1.0f.
// Deterministic IEEE ops -> bit-identical everywhere it is evaluated.
__device__ __forceinline__ float edgeval(float lo, float d, int k) {
    float tt = (k == NBINS) ? 1.0f : __fmul_rn((float)k, 0.01f);
    return __fadd_rn(lo, __fmul_rn(d, tt));
}

// K1: per-feature min/max partials over combined=[z;cl] (float4); zero counts.
__global__ __launch_bounds__(256) void k_minmax(const float4* __restrict__ z4,
                                                const float4* __restrict__ cl4,
                                                int zn4, int total4,
                                                unsigned* __restrict__ partials,
                                                unsigned* __restrict__ counts) {
    int gtid = blockIdx.x * 256 + threadIdx.x;
    if (gtid < FF * NBINS) counts[gtid] = 0u;   // zero for K2's atomics

    unsigned mn[4] = {~0u, ~0u, ~0u, ~0u}, mx[4] = {0u, 0u, 0u, 0u};
    int stride = MM_BLOCKS * 256;               // float4 units; 4*stride % 16 == 0
    for (int i = gtid; i < total4; i += stride) {
        float4 v = (i < zn4) ? z4[i] : cl4[i - zn4];
        unsigned e;
        e = enc_f(v.x); mn[0] = min(mn[0], e); mx[0] = max(mx[0], e);
        e = enc_f(v.y); mn[1] = min(mn[1], e); mx[1] = max(mx[1], e);
        e = enc_f(v.z); mn[2] = min(mn[2], e); mx[2] = max(mx[2], e);
        e = enc_f(v.w); mn[3] = min(mn[3], e); mx[3] = max(mx[3], e);
    }
    // lane l, component c covers feature (4l+c)&15; lanes l and l^4 share features
#pragma unroll
    for (int off = 4; off < 64; off <<= 1) {
#pragma unroll
        for (int c = 0; c < 4; ++c) {
            mn[c] = min(mn[c], shfl_xor_u(mn[c], off));
            mx[c] = max(mx[c], shfl_xor_u(mx[c], off));
        }
    }
    __shared__ unsigned smin[4][16], smax[4][16];
    int wave = threadIdx.x >> 6, lane = threadIdx.x & 63;
    if (lane < 4) {
#pragma unroll
        for (int c = 0; c < 4; ++c) {
            smin[wave][4 * lane + c] = mn[c];
            smax[wave][4 * lane + c] = mx[c];
        }
    }
    __syncthreads();
    if (threadIdx.x < 16) {
        int f = threadIdx.x;
        partials[blockIdx.x * 32 + f] =
            min(min(smin[0][f], smin[1][f]), min(smin[2][f], smin[3][f]));
        partials[blockIdx.x * 32 + 16 + f] =
            max(max(smax[0][f], smax[1][f]), max(smax[2][f], smax[3][f]));
    }
}

// K2: histogram (searchsorted 'right'-1 clipped -> LDS atomics) AND side-left bin
// per element -> sbins (int8). Edges computed on the fly (pure VALU).
__global__ __launch_bounds__(256) void k_hist(const float4* __restrict__ z4,
                                              const float4* __restrict__ cl4,
                                              int zn4, int total4,
                                              const unsigned* __restrict__ partials,
                                              unsigned* __restrict__ counts,
                                              unsigned* __restrict__ sb32) {
    __shared__ unsigned ulo[16], uhi[16];
    __shared__ float slo[16], sd[16], sscl[16];
    __shared__ unsigned sc[FF * NBINS];
    int t = threadIdx.x;
    for (int i = t; i < FF * NBINS; i += 256) sc[i] = 0u;
    if (t < 16) { ulo[t] = ~0u; uhi[t] = 0u; }
    __syncthreads();
    {   // reduce 256-block partials: 16 chunks of 16 blocks
        int f = t & 15, b0 = (t >> 4) * (MM_BLOCKS / 16);
        unsigned um = ~0u, ux = 0u;
#pragma unroll
        for (int b = b0; b < b0 + MM_BLOCKS / 16; ++b) {
            um = min(um, partials[b * 32 + f]);
            ux = max(ux, partials[b * 32 + 16 + f]);
        }
        atomicMin(&ulo[f], um);
        atomicMax(&uhi[f], ux);
    }
    __syncthreads();
    if (t < 16) {
        float lo = dec_f(ulo[t]), hi = dec_f(uhi[t]);
        float d = __fsub_rn(hi, lo);
        slo[t] = lo; sd[t] = d;
        sscl[t] = d > 0.0f ? 100.0f / d : 0.0f;   // guess only; fixup is exact
    }
    __syncthreads();

    int gtid = blockIdx.x * 256 + t;
    int stride = HIST_BLOCKS * 256;               // 4*stride % 16 == 0
    int fb = (4 * gtid) & 15;                     // feature of component 0 (fixed)
    float lo_c[4], d_c[4], scl_c[4];
#pragma unroll
    for (int c = 0; c < 4; ++c) {
        int f = (fb + c) & 15;
        lo_c[c] = slo[f]; d_c[c] = sd[f]; scl_c[c] = sscl[f];
    }
    for (int i = gtid; i < total4; i += stride) {
        float4 v4 = (i < zn4) ? z4[i] : cl4[i - zn4];
        float vv[4] = {v4.x, v4.y, v4.z, v4.w};
        unsigned pack = 0u;
#pragma unroll
        for (int c = 0; c < 4; ++c) {
            int f = (fb + c) & 15;
            float v = vv[c], lo = lo_c[c], dd = d_c[c];
            int g = (int)((v - lo) * scl_c[c]);
            g = g < 0 ? 0 : (g > NBINS - 1 ? NBINS - 1 : g);
            while (g < NBINS - 1 && edgeval(lo, dd, g + 1) <= v) ++g;  // 'right'
            while (g > 0 && edgeval(lo, dd, g) > v) --g;
            atomicAdd(&sc[f * NBINS + g], 1u);
            // side-left bin: largest k with edge[k] < v (or -1); for k>g edge[k]>v
            int gl = g;
            while (gl >= 0 && edgeval(lo, dd, gl) >= v) --gl;
            pack |= ((unsigned)gl & 0xffu) << (8 * c);
        }
        sb32[i] = pack;                            // 4 int8 bins, coalesced
    }
    __syncthreads();
    for (int i = t; i < FF * NBINS; i += 256) {
        unsigned c = sc[i];
        if (c) atomicAdd(&counts[i], c);
    }
}

// K3: counts -> cumsum; cluster (Qc,Pc) from sbins tail; per-sample output.
// scnt(s,cb) = max(Qs,Qc) - min(Ps,Pc)  (exact identity, Q/P monotone in bin)
__global__ __launch_bounds__(256) void k_main(const signed char* __restrict__ sbins,
                                              int N, float inv_div,
                                              const unsigned* __restrict__ counts,
                                              float* __restrict__ out) {
    __shared__ unsigned scnt[FF * NBINS];
    __shared__ float scum[FF * NBINS];
    __shared__ float sqpf[CC * 32];     // [c][2f]=Qc, [c][2f+1]=Pc
    int t = threadIdx.x;
    for (int i = t; i < FF * NBINS; i += 256) scnt[i] = counts[i];
    __syncthreads();
    if (t < 16) {                                  // serial cumsum, exact (< 2^24)
        float s = 0.0f;
        const unsigned* cp = &scnt[t * NBINS];
        float* fp = &scum[t * NBINS];
#pragma unroll
        for (int k = 0; k < NBINS; ++k) { s += (float)cp[k]; fp[k] = s; }
    }
    __syncthreads();
    {                                              // 256 threads = 16c x 16f
        int c = t >> 4, f = t & 15;
        int g = (int)sbins[(size_t)(N + c) * FF + f];
        sqpf[c * 32 + 2 * f]     = scum[f * NBINS + (g < 0 ? 0 : g)];
        sqpf[c * 32 + 2 * f + 1] = (g >= 1) ? scum[f * NBINS + g - 1] : 0.0f;
    }
    __syncthreads();

    int n = blockIdx.x * 256 + t;
    if (n >= N) return;

    const int4* br = (const int4*)(sbins + (size_t)n * FF);
    int4 w = *br;
    int gs[FF];
    gs[0]  = (w.x << 24) >> 24; gs[1]  = (w.x << 16) >> 24;
    gs[2]  = (w.x << 8)  >> 24; gs[3]  =  w.x >> 24;
    gs[4]  = (w.y << 24) >> 24; gs[5]  = (w.y << 16) >> 24;
    gs[6]  = (w.y << 8)  >> 24; gs[7]  =  w.y >> 24;
    gs[8]  = (w.z << 24) >> 24; gs[9]  = (w.z << 16) >> 24;
    gs[10] = (w.z << 8)  >> 24; gs[11] =  w.z >> 24;
    gs[12] = (w.w << 24) >> 24; gs[13] = (w.w << 16) >> 24;
    gs[14] = (w.w << 8)  >> 24; gs[15] =  w.w >> 24;

    float Qs[FF], Ps[FF];
#pragma unroll
    for (int f = 0; f < FF; ++f) {
        int g = gs[f];
        Qs[f] = scum[f * NBINS + (g < 0 ? 0 : g)];
        Ps[f] = (g >= 1) ? scum[f * NBINS + g - 1] : 0.0f;
    }

    float q[CC];
    float rowsum = 0.0f;
#pragma unroll
    for (int c = 0; c < CC; ++c) {
        float acc = 0.0f;
        const float4* qprow = (const float4*)&sqpf[c * 32];
#pragma unroll
        for (int f2 = 0; f2 < 8; ++f2) {
            float4 qp = qprow[f2];                 // wave-uniform -> LDS broadcast
            float h0 = fmaxf(Qs[2 * f2], qp.x);
            float l0 = fminf(Ps[2 * f2], qp.y);
            float d0 = h0 - l0;
            acc = fmaf(d0, d0, acc);
            float h1 = fmaxf(Qs[2 * f2 + 1], qp.z);
            float l1 = fminf(Ps[2 * f2 + 1], qp.w);
            float d1 = h1 - l1;
            acc = fmaf(d1, d1, acc);
        }
        float mass = sqrtf(acc) * inv_div;
        float qq = 1.0f / (1.0f + mass);
        q[c] = qq;
        rowsum += qq;
    }

    float* op = out + (size_t)n * CC;
    float4 o;
    o.x = q[0] / rowsum;  o.y = q[1] / rowsum;  o.z = q[2] / rowsum;  o.w = q[3] / rowsum;
    ((float4*)op)[0] = o;
    o.x = q[4] / rowsum;  o.y = q[5] / rowsum;  o.z = q[6] / rowsum;  o.w = q[7] / rowsum;
    ((float4*)op)[1] = o;
    o.x = q[8] / rowsum;  o.y = q[9] / rowsum;  o.z = q[10] / rowsum; o.w = q[11] / rowsum;
    ((float4*)op)[2] = o;
    o.x = q[12] / rowsum; o.y = q[13] / rowsum; o.z = q[14] / rowsum; o.w = q[15] / rowsum;
    ((float4*)op)[3] = o;
}

extern "C" void kernel_launch(void* const* d_in, const int* in_sizes, int n_in,
                              void* d_out, int out_size, void* d_ws, size_t ws_size,
                              hipStream_t stream) {
    const float* z  = (const float*)d_in[0];
    const float* cl = (const float*)d_in[1];
    float* out = (float*)d_out;
    int N = in_sizes[0] / FF;

    char* ws = (char*)d_ws;
    unsigned*    partials = (unsigned*)(ws);
    unsigned*    counts   = (unsigned*)(ws + 32768);
    signed char* sbins    = (signed char*)(ws + 39168);

    int zn4 = N * FF / 4;
    int total4 = (N + CC) * FF / 4;
    float inv_div = 1.0f / (float)(N + CC);

    k_minmax<<<MM_BLOCKS, 256, 0, stream>>>((const float4*)z, (const float4*)cl,
                                            zn4, total4, partials, counts);
    k_hist<<<HIST_BLOCKS, 256, 0, stream>>>((const float4*)z, (const float4*)cl,
                                            zn4, total4, partials, counts,
                                            (unsigned*)sbins);
    int blocks = (N + 255) / 256;
    k_main<<<blocks, 256, 0, stream>>>(sbins, N, inv_div, counts, out);
}